// Round 13
// baseline (194.415 us; speedup 1.0000x reference)
//
#include <hip/hip_runtime.h>

typedef _Float16 f16;
typedef _Float16 f16x8 __attribute__((ext_vector_type(8)));
typedef float f32x4 __attribute__((ext_vector_type(4)));
typedef unsigned short u16;
typedef unsigned int u32;
typedef u32 u32x4 __attribute__((ext_vector_type(4)));

// ---- workspace layout (bytes) ----
#define WS_BN1_INV  256u       // 256 f32
#define WS_BN1_BETA 1280u
#define WS_BN2_INV  2304u
#define WS_BN2_BETA 3328u
#define WS_BN3_INV  4352u      // 1024 f32
#define WS_BN3_BETA 8448u
#define WS_PEG_B    12544u     // 256 f32
#define WS_PEGQ     13568u     // [9][256] f16
#define WS_W1Q      18432u     // [256 co][1024 ci] f16
#define WS_W3Q      542720u    // [1024 co][256 ci] f16
#define WS_W2Q      1067008u   // [9 tap][256 co][256 ci] f16
#define WS_H1T      2246656u   // [32768 p][256 c] f16 (h1; reused as h3T after peg)
#define WS_H2T      19023872u  // [32768 p][256 c] f16

// r11: activation fake-quant subsumed by f16 storage rounding — removed (-66us).
// r12: XCD decode on conv3 raised FETCH 80->101MB — reverted to linear bid.

__device__ __forceinline__ int badf(float f){
  union { float f; u32 u; } c; c.f = f;
  return (c.u & 0x7f800000u) == 0x7f800000u;
}
// DeepShift pow2 weight quant: sign(w)*2^clip(round(log2|w|), -14, 0)
__device__ __forceinline__ float qpow2(float w){
  float a = fabsf(w) + 1e-20f;
  float p = rintf(log2f(a));
  p = fminf(fmaxf(p, -14.0f), 0.0f);
  float m = exp2f(p);
  return (w > 0.0f) ? m : ((w < 0.0f) ? -m : 0.0f);
}
#define SWZ(row, slot) ((((slot) ^ ((row) >> 1) ^ ((row) >> 3))) & 3)

__device__ __forceinline__ void mfma_step(const char* lds, int wm, int wn,
                                          int lr, int lg, f32x4 acc[4][4]){
  f16x8 a[4], bb[4];
  #pragma unroll
  for (int mf = 0; mf < 4; ++mf){
    int row = (wm << 6) + (mf << 4) + lr;
    a[mf] = *(const f16x8*)(lds + (row << 6) + (SWZ(row, lg) << 4));
  }
  #pragma unroll
  for (int nf = 0; nf < 4; ++nf){
    int row = (wn << 6) + (nf << 4) + lr;
    bb[nf] = *(const f16x8*)(lds + 8192 + (row << 6) + (SWZ(row, lg) << 4));
  }
  #pragma unroll
  for (int mf = 0; mf < 4; ++mf)
    #pragma unroll
    for (int nf = 0; nf < 4; ++nf)
      acc[mf][nf] = __builtin_amdgcn_mfma_f32_16x16x32_f16(a[mf], bb[nf], acc[mf][nf], 0, 0, 0);
}

// ---- prep: quantize all weights to f16 pow2, precompute BN affine ----
__global__ __launch_bounds__(256) void prep_kernel(
    const float* __restrict__ w1, const float* __restrict__ pegw, const float* __restrict__ pegb,
    const float* __restrict__ w2, const float* __restrict__ w3,
    const float* g1, const float* b1, const float* m1, const float* v1,
    const float* g2, const float* b2, const float* m2, const float* v2,
    const float* g3, const float* b3, const float* m3, const float* v3,
    char* ws){
  int i = blockIdx.x * 256 + threadIdx.x;
  if (i < 262144){ ((f16*)(ws + WS_W1Q))[i] = (f16)qpow2(w1[i]); return; }
  i -= 262144;
  if (i < 589824){ // repack OIHW -> [tap][co][ci]
    int tap = i >> 16, rem = i & 65535;
    int co = rem >> 8, ci = rem & 255;
    ((f16*)(ws + WS_W2Q))[i] = (f16)qpow2(w2[(((co << 8) + ci) * 9) + tap]);
    return;
  }
  i -= 589824;
  if (i < 262144){ ((f16*)(ws + WS_W3Q))[i] = (f16)qpow2(w3[i]); return; }
  i -= 262144;
  if (i < 2304){ // [c][tap] -> [tap][c]
    int tap = i >> 8, c = i & 255;
    ((f16*)(ws + WS_PEGQ))[i] = (f16)qpow2(pegw[c * 9 + tap]);
    return;
  }
  i -= 2304;
  if (i < 256){ ((float*)(ws + WS_PEG_B))[i] = pegb[i]; return; }
  i -= 256;
  if (i < 256){
    float inv = g1[i] / sqrtf(v1[i] + 1e-5f);
    ((float*)(ws + WS_BN1_INV))[i] = inv;
    ((float*)(ws + WS_BN1_BETA))[i] = b1[i] - m1[i] * inv;
    return;
  }
  i -= 256;
  if (i < 256){
    float inv = g2[i] / sqrtf(v2[i] + 1e-5f);
    ((float*)(ws + WS_BN2_INV))[i] = inv;
    ((float*)(ws + WS_BN2_BETA))[i] = b2[i] - m2[i] * inv;
    return;
  }
  i -= 256;
  if (i < 1024){
    float inv = g3[i] / sqrtf(v3[i] + 1e-5f);
    ((float*)(ws + WS_BN3_INV))[i] = inv;
    ((float*)(ws + WS_BN3_BETA))[i] = b3[i] - m3[i] * inv;
  }
}

// ---- conv1: 1x1 1024->256. Block = 128 px x FULL 256 co, 8 waves. ----
__global__ __launch_bounds__(512) void conv1_kernel(const float* __restrict__ x, char* ws){
  __shared__ __align__(16) char lds[24576];   // A 128x32 f16 (8KB) + B 256x32 f16 (16KB)
  const f16* w1q = (const f16*)(ws + WS_W1Q);
  f16* h1T = (f16*)(ws + WS_H1T);

  int tid = threadIdx.x, bid = blockIdx.x;
  int b = bid >> 3, m0 = (bid & 7) << 7;
  int l = tid & 63, wid = tid >> 6, wm = wid >> 2, wn = wid & 3;
  int lr = l & 15, lg = l >> 4;
  f32x4 acc[4][4] = {};

  int pblk = tid & 15;   // 16 pixel-blocks of 8
  int cil  = tid >> 4;   // 32 ci rows per pass

  for (int ks = 0; ks < 32; ++ks){
    int k0 = ks << 5;
    // stage A: x[b][k0+cil][m0 + p] -> As[p][ci] (transpose, f16 cast)
    {
      const float* src = x + (((size_t)(b << 10) + k0 + cil) << 10) + m0 + (pblk << 3);
      f32x4 d0 = *(const f32x4*)src;
      f32x4 d1 = *(const f32x4*)(src + 4);
      #pragma unroll
      for (int j = 0; j < 8; ++j){
        float xv = (j < 4) ? d0[j] : d1[j - 4];
        int row = (pblk << 3) + j;
        *(f16*)(lds + (row << 6) + (SWZ(row, cil >> 3) << 4) + ((cil & 7) << 1)) = (f16)xv;
      }
    }
    // stage B: w1q[row][k0 + slot*8], 256 rows x 64B
    #pragma unroll
    for (int i = 0; i < 2; ++i){
      int s = tid + (i << 9);
      int row = s >> 2, slot = s & 3;
      u32x4 d = *(const u32x4*)(w1q + ((size_t)row << 10) + k0 + (slot << 3));
      *(u32x4*)(lds + 8192 + (row << 6) + (SWZ(row, slot) << 4)) = d;
    }
    __syncthreads();
    f16x8 a[4], bb[4];
    #pragma unroll
    for (int mf = 0; mf < 4; ++mf){
      int row = (wm << 6) + (mf << 4) + lr;
      a[mf] = *(const f16x8*)(lds + (row << 6) + (SWZ(row, lg) << 4));
    }
    #pragma unroll
    for (int nf = 0; nf < 4; ++nf){
      int row = (wn << 6) + (nf << 4) + lr;
      bb[nf] = *(const f16x8*)(lds + 8192 + (row << 6) + (SWZ(row, lg) << 4));
    }
    #pragma unroll
    for (int mf = 0; mf < 4; ++mf)
      #pragma unroll
      for (int nf = 0; nf < 4; ++nf)
        acc[mf][nf] = __builtin_amdgcn_mfma_f32_16x16x32_f16(a[mf], bb[nf], acc[mf][nf], 0, 0, 0);
    __syncthreads();
  }

  #pragma unroll
  for (int mf = 0; mf < 4; ++mf){
    int p0 = m0 + (wm << 6) + (mf << 4) + (lg << 2);
    size_t base = ((size_t)(b << 10) + p0) << 8;
    #pragma unroll
    for (int nf = 0; nf < 4; ++nf){
      int co = (wn << 6) + (nf << 4) + lr;
      #pragma unroll
      for (int r = 0; r < 4; ++r)
        h1T[base + ((size_t)r << 8) + co] = (f16)acc[mf][nf][r];
    }
  }
}

// ---- PEG: depthwise 3x3, block = one (batch,row); staging is a pure copy ----
__global__ __launch_bounds__(256) void peg_kernel(char* ws){
  __shared__ __align__(16) f16 tile[3][32][256];   // 48 KB
  const f16* h1T = (const f16*)(ws + WS_H1T);
  const f16* pegq = (const f16*)(ws + WS_PEGQ);
  const float* pb  = (const float*)(ws + WS_PEG_B);
  const float* inv1 = (const float*)(ws + WS_BN1_INV);
  const float* bt1  = (const float*)(ws + WS_BN1_BETA);
  f16* h2T = (f16*)(ws + WS_H2T);

  int tid = threadIdx.x;
  int b = blockIdx.x >> 5, h = blockIdx.x & 31;

  #pragma unroll
  for (int r = 0; r < 3; ++r){
    int hh = h + r - 1;
    #pragma unroll
    for (int i = 0; i < 4; ++i){
      int chunk = tid + (i << 8);          // 0..1023
      int px = chunk >> 5, cg = chunk & 31;
      u32x4 d = {0u, 0u, 0u, 0u};
      if ((u32)hh < 32u)
        d = *(const u32x4*)(h1T + (((size_t)(b << 10) + (hh << 5) + px) << 8) + (cg << 3));
      *(u32x4*)(&tile[r][px][cg << 3]) = d;
    }
  }
  __syncthreads();

  int c0 = (tid & 31) << 3;   // 8 channels
  int q  = tid >> 5;          // pixel quad: px = 4q..4q+3
  float acc[4][8];
  #pragma unroll
  for (int i = 0; i < 4; ++i)
    #pragma unroll
    for (int j = 0; j < 8; ++j) acc[i][j] = pb[c0 + j];

  #pragma unroll
  for (int ky = 0; ky < 3; ++ky){
    #pragma unroll
    for (int kx = 0; kx < 3; ++kx){
      f16x8 wv = *(const f16x8*)(pegq + ((ky * 3 + kx) << 8) + c0);
      #pragma unroll
      for (int i = 0; i < 4; ++i){
        int ww = (q << 2) + i + kx - 1;
        if ((u32)ww < 32u){
          f16x8 v = *(const f16x8*)(&tile[ky][ww][c0]);
          #pragma unroll
          for (int j = 0; j < 8; ++j) acc[i][j] += (float)v[j] * (float)wv[j];
        }
      }
    }
  }

  f32x4 iv0 = *(const f32x4*)(inv1 + c0), iv1 = *(const f32x4*)(inv1 + c0 + 4);
  f32x4 bt0 = *(const f32x4*)(bt1 + c0),  bt1v = *(const f32x4*)(bt1 + c0 + 4);
  #pragma unroll
  for (int i = 0; i < 4; ++i){
    f16x8 o;
    #pragma unroll
    for (int j = 0; j < 8; ++j){
      float ivj = (j < 4) ? iv0[j] : iv1[j - 4];
      float btj = (j < 4) ? bt0[j] : bt1v[j - 4];
      o[j] = (f16)fmaxf(acc[i][j] * ivj + btj, 0.0f);
    }
    int p = (h << 5) + (q << 2) + i;
    *(f16x8*)(h2T + (((size_t)(b << 10) + p) << 8) + c0) = o;
  }
}

// ---- conv2: 3x3 256->256. Block = 128 px x full 256 co, 8 waves; A staged
// once (pure copy); B double-buffered. bn2+relu -> h3T (WS_H1T region). ----
__global__ __launch_bounds__(512) void conv2_kernel(char* ws){
  __shared__ __align__(16) char lds[104448 + 32768];
  const f16* h2T = (const f16*)(ws + WS_H2T);
  const f16* w2q = (const f16*)(ws + WS_W2Q);
  const float* inv2 = (const float*)(ws + WS_BN2_INV);
  const float* bt2  = (const float*)(ws + WS_BN2_BETA);
  f16* h3T = (f16*)(ws + WS_H1T);

  int tid = threadIdx.x, bid = blockIdx.x;
  int b = bid >> 3, mt = bid & 7;
  int h0 = mt << 2;
  int m0 = mt << 7;
  int l = tid & 63, wid = tid >> 6, wm = wid >> 2, wn = wid & 3;
  int lr = l & 15, lg = l >> 4;
  char* A = lds;
  char* B0 = lds + 104448;
  char* B1 = lds + 104448 + 16384;

  for (int chunk = tid; chunk < 6528; chunk += 512){
    int r = chunk / 1088;
    int rem = chunk - r * 1088;
    int cc = rem >> 5, slot = rem & 31;
    int hh = h0 - 1 + r, wwp = cc - 1;
    u32x4 d = {0u, 0u, 0u, 0u};
    if ((u32)hh < 32u && (u32)wwp < 32u)
      d = *(const u32x4*)(h2T + (((size_t)(b << 10) + (hh << 5) + wwp) << 8) + (slot << 3));
    int sw = slot ^ ((cc & 7) << 2);
    *(u32x4*)(A + ((r * 34 + cc) << 9) + (sw << 4)) = d;
  }
  #pragma unroll
  for (int i = 0; i < 2; ++i){
    int chunk = tid + (i << 9);
    int co = chunk >> 2, slot = chunk & 3;
    u32x4 d = *(const u32x4*)(w2q + (co << 8) + (slot << 3));
    *(u32x4*)(B0 + (co << 6) + (SWZ(co, slot) << 4)) = d;
  }
  __syncthreads();

  f32x4 acc[4][4] = {};
  for (int tap = 0; tap < 9; ++tap){
    int dy = tap / 3 - 1, dx = tap % 3 - 1;
    int rowbase[4], key[4];
    #pragma unroll
    for (int mf = 0; mf < 4; ++mf){
      int p = (wm << 6) + (mf << 4) + lr;
      int rr = (p >> 5) + dy + 1;
      int cc = (p & 31) + dx + 1;
      rowbase[mf] = ((rr * 34 + cc) << 9) + (lg << 4);
      key[mf] = cc & 7;
    }
    #pragma unroll 2
    for (int ks = 0; ks < 8; ++ks){
      int t = (tap << 3) + ks;
      u32x4 st[2];
      int have = (t < 71);
      int t1 = t + 1, wtap = t1 >> 3, wks = t1 & 7;
      const f16* srcb = w2q + wtap * 65536 + (wks << 5);
      if (have){
        #pragma unroll
        for (int i = 0; i < 2; ++i){
          int chunk = tid + (i << 9);
          int co = chunk >> 2, slot = chunk & 3;
          st[i] = *(const u32x4*)(srcb + (co << 8) + (slot << 3));
        }
      }
      const char* bs = (t & 1) ? B1 : B0;
      f16x8 a[4], bb[4];
      #pragma unroll
      for (int mf = 0; mf < 4; ++mf)
        a[mf] = *(const f16x8*)(A + rowbase[mf] + ((ks ^ key[mf]) << 6));
      #pragma unroll
      for (int nf = 0; nf < 4; ++nf){
        int row = (wn << 6) + (nf << 4) + lr;
        bb[nf] = *(const f16x8*)(bs + (row << 6) + (SWZ(row, lg) << 4));
      }
      #pragma unroll
      for (int mf = 0; mf < 4; ++mf)
        #pragma unroll
        for (int nf = 0; nf < 4; ++nf)
          acc[mf][nf] = __builtin_amdgcn_mfma_f32_16x16x32_f16(a[mf], bb[nf], acc[mf][nf], 0, 0, 0);
      if (have){
        char* bd = (t1 & 1) ? B1 : B0;
        #pragma unroll
        for (int i = 0; i < 2; ++i){
          int chunk = tid + (i << 9);
          int co = chunk >> 2, slot = chunk & 3;
          *(u32x4*)(bd + (co << 6) + (SWZ(co, slot) << 4)) = st[i];
        }
      }
      __syncthreads();
    }
  }

  #pragma unroll
  for (int mf = 0; mf < 4; ++mf){
    int p0 = m0 + (wm << 6) + (mf << 4) + (lg << 2);
    size_t base = ((size_t)(b << 10) + p0) << 8;
    #pragma unroll
    for (int nf = 0; nf < 4; ++nf){
      int co = (wn << 6) + (nf << 4) + lr;
      float iv = inv2[co], bt = bt2[co];
      #pragma unroll
      for (int r = 0; r < 4; ++r)
        h3T[base + ((size_t)r << 8) + co] = (f16)fmaxf(acc[mf][nf][r] * iv + bt, 0.0f);
    }
  }
}

// ---- conv3: 1x1 256->1024. Tile DOUBLED: 128 co x 256 px, 512 thr / 8 waves
// (wm: 2 co-halves, wn: 4 px-quarters). Grid 1024, linear bid -> 4 blocks/CU
// co-resident so epilogue x/out streams overlap other blocks' K-loops. ----
__global__ __launch_bounds__(512) void conv3_kernel(const float* __restrict__ x,
                                                    float* __restrict__ out, char* ws){
  __shared__ __align__(16) char lds[24576];   // A 128x32 (8KB) + B 256x32 (16KB)
  const f16* w3q = (const f16*)(ws + WS_W3Q);
  const f16* h3T = (const f16*)(ws + WS_H1T);
  const float* inv3 = (const float*)(ws + WS_BN3_INV);
  const float* bt3  = (const float*)(ws + WS_BN3_BETA);

  int tid = threadIdx.x, bid = blockIdx.x;
  int n4 = bid & 3, m0i = (bid >> 2) & 7, b = bid >> 5;
  int m0 = m0i << 7;        // co base
  int n0 = n4 << 8;         // px base (256-px tile)
  int l = tid & 63, wid = tid >> 6, wm = wid >> 2, wn = wid & 3;
  int lr = l & 15, lg = l >> 4;
  f32x4 acc[4][4] = {};

  for (int ks = 0; ks < 8; ++ks){
    int k0 = ks << 5;
    // stage A: w3q[m0+row][k0..], 128 rows (1 chunk/thread)
    {
      int row = tid >> 2, slot = tid & 3;
      u32x4 dA = *(const u32x4*)(w3q + ((size_t)(m0 + row) << 8) + k0 + (slot << 3));
      *(u32x4*)(lds + (row << 6) + (SWZ(row, slot) << 4)) = dA;
    }
    // stage B: h3T[(b<<10)+n0+row][k0..], 256 rows (2 chunks/thread)
    #pragma unroll
    for (int i = 0; i < 2; ++i){
      int s = tid + (i << 9);
      int row = s >> 2, slot = s & 3;
      u32x4 dB = *(const u32x4*)(h3T + (((size_t)(b << 10) + n0 + row) << 8) + k0 + (slot << 3));
      *(u32x4*)(lds + 8192 + (row << 6) + (SWZ(row, slot) << 4)) = dB;
    }
    __syncthreads();
    f16x8 a[4], bb[4];
    #pragma unroll
    for (int mf = 0; mf < 4; ++mf){
      int row = (wm << 6) + (mf << 4) + lr;
      a[mf] = *(const f16x8*)(lds + (row << 6) + (SWZ(row, lg) << 4));
    }
    #pragma unroll
    for (int nf = 0; nf < 4; ++nf){
      int row = (wn << 6) + (nf << 4) + lr;
      bb[nf] = *(const f16x8*)(lds + 8192 + (row << 6) + (SWZ(row, lg) << 4));
    }
    #pragma unroll
    for (int mf = 0; mf < 4; ++mf)
      #pragma unroll
      for (int nf = 0; nf < 4; ++nf)
        acc[mf][nf] = __builtin_amdgcn_mfma_f32_16x16x32_f16(a[mf], bb[nf], acc[mf][nf], 0, 0, 0);
    __syncthreads();
  }

  #pragma unroll
  for (int mf = 0; mf < 4; ++mf){
    int co0 = m0 + (wm << 6) + (mf << 4) + (lg << 2);
    f32x4 iv = *(const f32x4*)(inv3 + co0);
    f32x4 bt = *(const f32x4*)(bt3 + co0);
    #pragma unroll
    for (int nf = 0; nf < 4; ++nf){
      int p = n0 + (wn << 6) + (nf << 4) + lr;
      #pragma unroll
      for (int r = 0; r < 4; ++r){
        size_t idx = (((size_t)(b << 10) + co0 + r) << 10) + p;
        float z = acc[mf][nf][r] * iv[r] + bt[r] + x[idx];
        float rr = fmaxf(z, 0.0f);
        if (badf(z)) rr = 512.0f;
        out[idx] = rr;
      }
    }
  }
}

extern "C" void kernel_launch(void* const* d_in, const int* in_sizes, int n_in,
                              void* d_out, int out_size, void* d_ws, size_t ws_size,
                              hipStream_t stream){
  const float* x    = (const float*)d_in[0];
  const float* w1   = (const float*)d_in[1];
  const float* pegw = (const float*)d_in[2];
  const float* pegb = (const float*)d_in[3];
  const float* w2   = (const float*)d_in[4];
  const float* w3   = (const float*)d_in[5];
  const float* g1 = (const float*)d_in[6];
  const float* b1 = (const float*)d_in[7];
  const float* m1 = (const float*)d_in[8];
  const float* v1 = (const float*)d_in[9];
  const float* g2 = (const float*)d_in[10];
  const float* b2 = (const float*)d_in[11];
  const float* m2 = (const float*)d_in[12];
  const float* v2 = (const float*)d_in[13];
  const float* g3 = (const float*)d_in[14];
  const float* b3 = (const float*)d_in[15];
  const float* m3 = (const float*)d_in[16];
  const float* v3 = (const float*)d_in[17];
  char* ws = (char*)d_ws;

  prep_kernel<<<4368, 256, 0, stream>>>(w1, pegw, pegb, w2, w3,
                                        g1, b1, m1, v1, g2, b2, m2, v2,
                                        g3, b3, m3, v3, ws);
  conv1_kernel<<<256, 512, 0, stream>>>(x, ws);
  peg_kernel<<<1024, 256, 0, stream>>>(ws);
  conv2_kernel<<<256, 512, 0, stream>>>(ws);
  conv3_kernel<<<1024, 512, 0, stream>>>(x, (float*)d_out, ws);
}

// Round 14
// 177.436 us; speedup vs baseline: 1.0957x; 1.0957x over previous
//
#include <hip/hip_runtime.h>

typedef _Float16 f16;
typedef _Float16 f16x8 __attribute__((ext_vector_type(8)));
typedef float f32x4 __attribute__((ext_vector_type(4)));
typedef unsigned short u16;
typedef unsigned int u32;
typedef u32 u32x4 __attribute__((ext_vector_type(4)));

// ---- workspace layout (bytes) ----
#define WS_BN1_INV  256u       // 256 f32
#define WS_BN1_BETA 1280u
#define WS_BN2_INV  2304u
#define WS_BN2_BETA 3328u
#define WS_BN3_INV  4352u      // 1024 f32
#define WS_BN3_BETA 8448u
#define WS_PEG_B    12544u     // 256 f32
#define WS_PEGQ     13568u     // [9][256] f16
#define WS_W1Q      18432u     // [256 co][1024 ci] f16
#define WS_W3Q      542720u    // [1024 co][256 ci] f16
#define WS_W2Q      1067008u   // [9 tap][256 co][256 ci] f16
#define WS_H1T      2246656u   // [32768 p][256 c] f16 (h1; reused as h3T after peg)
#define WS_H2T      19023872u  // [32768 p][256 c] f16

// r11: activation fake-quant subsumed by f16 storage rounding — removed (-66us).
// r12: XCD decode on conv3 raised FETCH 80->101MB — linear bid.
// r13: conv3 256px tile regressed (87 vs 77) — R10 shape is the plateau.

__device__ __forceinline__ int badf(float f){
  union { float f; u32 u; } c; c.f = f;
  return (c.u & 0x7f800000u) == 0x7f800000u;
}
// DeepShift pow2 weight quant: sign(w)*2^clip(round(log2|w|), -14, 0)
__device__ __forceinline__ float qpow2(float w){
  float a = fabsf(w) + 1e-20f;
  float p = rintf(log2f(a));
  p = fminf(fmaxf(p, -14.0f), 0.0f);
  float m = exp2f(p);
  return (w > 0.0f) ? m : ((w < 0.0f) ? -m : 0.0f);
}
__device__ __forceinline__ u32 pack2(float a, float b){
  union { f16 h[2]; u32 u; } p; p.h[0] = (f16)a; p.h[1] = (f16)b; return p.u;
}
#define SWZ(row, slot) ((((slot) ^ ((row) >> 1) ^ ((row) >> 3))) & 3)

__device__ __forceinline__ void mfma_step(const char* lds, int wm, int wn,
                                          int lr, int lg, f32x4 acc[4][4]){
  f16x8 a[4], bb[4];
  #pragma unroll
  for (int mf = 0; mf < 4; ++mf){
    int row = (wm << 6) + (mf << 4) + lr;
    a[mf] = *(const f16x8*)(lds + (row << 6) + (SWZ(row, lg) << 4));
  }
  #pragma unroll
  for (int nf = 0; nf < 4; ++nf){
    int row = (wn << 6) + (nf << 4) + lr;
    bb[nf] = *(const f16x8*)(lds + 8192 + (row << 6) + (SWZ(row, lg) << 4));
  }
  #pragma unroll
  for (int mf = 0; mf < 4; ++mf)
    #pragma unroll
    for (int nf = 0; nf < 4; ++nf)
      acc[mf][nf] = __builtin_amdgcn_mfma_f32_16x16x32_f16(a[mf], bb[nf], acc[mf][nf], 0, 0, 0);
}

// ---- prep: quantize all weights to f16 pow2, precompute BN affine ----
__global__ __launch_bounds__(256) void prep_kernel(
    const float* __restrict__ w1, const float* __restrict__ pegw, const float* __restrict__ pegb,
    const float* __restrict__ w2, const float* __restrict__ w3,
    const float* g1, const float* b1, const float* m1, const float* v1,
    const float* g2, const float* b2, const float* m2, const float* v2,
    const float* g3, const float* b3, const float* m3, const float* v3,
    char* ws){
  int i = blockIdx.x * 256 + threadIdx.x;
  if (i < 262144){ ((f16*)(ws + WS_W1Q))[i] = (f16)qpow2(w1[i]); return; }
  i -= 262144;
  if (i < 589824){ // repack OIHW -> [tap][co][ci]
    int tap = i >> 16, rem = i & 65535;
    int co = rem >> 8, ci = rem & 255;
    ((f16*)(ws + WS_W2Q))[i] = (f16)qpow2(w2[(((co << 8) + ci) * 9) + tap]);
    return;
  }
  i -= 589824;
  if (i < 262144){ ((f16*)(ws + WS_W3Q))[i] = (f16)qpow2(w3[i]); return; }
  i -= 262144;
  if (i < 2304){ // [c][tap] -> [tap][c]
    int tap = i >> 8, c = i & 255;
    ((f16*)(ws + WS_PEGQ))[i] = (f16)qpow2(pegw[c * 9 + tap]);
    return;
  }
  i -= 2304;
  if (i < 256){ ((float*)(ws + WS_PEG_B))[i] = pegb[i]; return; }
  i -= 256;
  if (i < 256){
    float inv = g1[i] / sqrtf(v1[i] + 1e-5f);
    ((float*)(ws + WS_BN1_INV))[i] = inv;
    ((float*)(ws + WS_BN1_BETA))[i] = b1[i] - m1[i] * inv;
    return;
  }
  i -= 256;
  if (i < 256){
    float inv = g2[i] / sqrtf(v2[i] + 1e-5f);
    ((float*)(ws + WS_BN2_INV))[i] = inv;
    ((float*)(ws + WS_BN2_BETA))[i] = b2[i] - m2[i] * inv;
    return;
  }
  i -= 256;
  if (i < 1024){
    float inv = g3[i] / sqrtf(v3[i] + 1e-5f);
    ((float*)(ws + WS_BN3_INV))[i] = inv;
    ((float*)(ws + WS_BN3_BETA))[i] = b3[i] - m3[i] * inv;
  }
}

// ---- conv1: 1x1 1024->256. Block = 128 px x FULL 256 co, 8 waves.
// DOUBLE-BUFFERED, 1 barrier/step (conv2's proven pattern): issue next
// K-slice loads -> MFMA(cur) -> write regs to nxt -> barrier.
// A-transpose staged as paired-ci u32 writes (half the LDS ops). ----
__global__ __launch_bounds__(512) void conv1_kernel(const float* __restrict__ x, char* ws){
  __shared__ __align__(16) char lds[49152];   // 2 x (A 8KB | B 16KB)
  const f16* w1q = (const f16*)(ws + WS_W1Q);
  f16* h1T = (f16*)(ws + WS_H1T);

  int tid = threadIdx.x, bid = blockIdx.x;
  int b = bid >> 3, m0 = (bid & 7) << 7;
  int l = tid & 63, wid = tid >> 6, wm = wid >> 2, wn = wid & 3;
  int lr = l & 15, lg = l >> 4;
  f32x4 acc[4][4] = {};

  int q = tid & 31;          // px-quad: px = 4q..4q+3 (coalesced x reads)
  int c = tid >> 5;          // ci-pair: ci = 2c, 2c+1 (16 pairs = 32 ci)
  const float* xb = x + (((size_t)(b << 10)) << 10) + m0 + (q << 2);
  // A write address (fixed per thread except row): slot = c>>2, in-slot ci off = (c&3)<<2
  int aslot = c >> 2, aoff = (c & 3) << 2;

  f32x4 d0, d1; u32x4 wb0, wb1;
  // prologue: load ks=0
  {
    const float* src = xb + (((size_t)(c << 1)) << 10);
    d0 = *(const f32x4*)src;
    d1 = *(const f32x4*)(src + 1024);
    int s0 = tid, r0 = s0 >> 2, sl0 = s0 & 3;
    int s1 = tid + 512, r1 = s1 >> 2, sl1 = s1 & 3;
    wb0 = *(const u32x4*)(w1q + ((size_t)r0 << 10) + (sl0 << 3));
    wb1 = *(const u32x4*)(w1q + ((size_t)r1 << 10) + (sl1 << 3));
  }
  // write ks=0 into buf0
  {
    char* A = lds;
    #pragma unroll
    for (int j = 0; j < 4; ++j){
      int row = (q << 2) + j;
      *(u32*)(A + (row << 6) + (SWZ(row, aslot) << 4) + aoff) = pack2(d0[j], d1[j]);
    }
    int s0 = tid, r0 = s0 >> 2, sl0 = s0 & 3;
    int s1 = tid + 512, r1 = s1 >> 2, sl1 = s1 & 3;
    *(u32x4*)(lds + 8192 + (r0 << 6) + (SWZ(r0, sl0) << 4)) = wb0;
    *(u32x4*)(lds + 8192 + (r1 << 6) + (SWZ(r1, sl1) << 4)) = wb1;
  }
  __syncthreads();

  for (int ks = 0; ks < 32; ++ks){
    const char* cur = lds + ((ks & 1) ? 24576 : 0);
    char* nxt = lds + ((ks & 1) ? 0 : 24576);
    // issue next K-slice global loads early
    if (ks < 31){
      int k0 = (ks + 1) << 5;
      const float* src = xb + (((size_t)(k0 + (c << 1))) << 10);
      d0 = *(const f32x4*)src;
      d1 = *(const f32x4*)(src + 1024);
      int s0 = tid, r0 = s0 >> 2, sl0 = s0 & 3;
      int s1 = tid + 512, r1 = s1 >> 2, sl1 = s1 & 3;
      wb0 = *(const u32x4*)(w1q + ((size_t)r0 << 10) + k0 + (sl0 << 3));
      wb1 = *(const u32x4*)(w1q + ((size_t)r1 << 10) + k0 + (sl1 << 3));
    }
    // MFMA on current buffer
    f16x8 a[4], bb[4];
    #pragma unroll
    for (int mf = 0; mf < 4; ++mf){
      int row = (wm << 6) + (mf << 4) + lr;
      a[mf] = *(const f16x8*)(cur + (row << 6) + (SWZ(row, lg) << 4));
    }
    #pragma unroll
    for (int nf = 0; nf < 4; ++nf){
      int row = (wn << 6) + (nf << 4) + lr;
      bb[nf] = *(const f16x8*)(cur + 8192 + (row << 6) + (SWZ(row, lg) << 4));
    }
    #pragma unroll
    for (int mf = 0; mf < 4; ++mf)
      #pragma unroll
      for (int nf = 0; nf < 4; ++nf)
        acc[mf][nf] = __builtin_amdgcn_mfma_f32_16x16x32_f16(a[mf], bb[nf], acc[mf][nf], 0, 0, 0);
    // late write of staged K-slice
    if (ks < 31){
      #pragma unroll
      for (int j = 0; j < 4; ++j){
        int row = (q << 2) + j;
        *(u32*)(nxt + (row << 6) + (SWZ(row, aslot) << 4) + aoff) = pack2(d0[j], d1[j]);
      }
      int s0 = tid, r0 = s0 >> 2, sl0 = s0 & 3;
      int s1 = tid + 512, r1 = s1 >> 2, sl1 = s1 & 3;
      *(u32x4*)(nxt + 8192 + (r0 << 6) + (SWZ(r0, sl0) << 4)) = wb0;
      *(u32x4*)(nxt + 8192 + (r1 << 6) + (SWZ(r1, sl1) << 4)) = wb1;
    }
    __syncthreads();
  }

  #pragma unroll
  for (int mf = 0; mf < 4; ++mf){
    int p0 = m0 + (wm << 6) + (mf << 4) + (lg << 2);
    size_t base = ((size_t)(b << 10) + p0) << 8;
    #pragma unroll
    for (int nf = 0; nf < 4; ++nf){
      int co = (wn << 6) + (nf << 4) + lr;
      #pragma unroll
      for (int r = 0; r < 4; ++r)
        h1T[base + ((size_t)r << 8) + co] = (f16)acc[mf][nf][r];
    }
  }
}

// ---- PEG: depthwise 3x3, block = one (batch,row); staging is a pure copy ----
__global__ __launch_bounds__(256) void peg_kernel(char* ws){
  __shared__ __align__(16) f16 tile[3][32][256];   // 48 KB
  const f16* h1T = (const f16*)(ws + WS_H1T);
  const f16* pegq = (const f16*)(ws + WS_PEGQ);
  const float* pb  = (const float*)(ws + WS_PEG_B);
  const float* inv1 = (const float*)(ws + WS_BN1_INV);
  const float* bt1  = (const float*)(ws + WS_BN1_BETA);
  f16* h2T = (f16*)(ws + WS_H2T);

  int tid = threadIdx.x;
  int b = blockIdx.x >> 5, h = blockIdx.x & 31;

  #pragma unroll
  for (int r = 0; r < 3; ++r){
    int hh = h + r - 1;
    #pragma unroll
    for (int i = 0; i < 4; ++i){
      int chunk = tid + (i << 8);          // 0..1023
      int px = chunk >> 5, cg = chunk & 31;
      u32x4 d = {0u, 0u, 0u, 0u};
      if ((u32)hh < 32u)
        d = *(const u32x4*)(h1T + (((size_t)(b << 10) + (hh << 5) + px) << 8) + (cg << 3));
      *(u32x4*)(&tile[r][px][cg << 3]) = d;
    }
  }
  __syncthreads();

  int c0 = (tid & 31) << 3;   // 8 channels
  int q  = tid >> 5;          // pixel quad: px = 4q..4q+3
  float acc[4][8];
  #pragma unroll
  for (int i = 0; i < 4; ++i)
    #pragma unroll
    for (int j = 0; j < 8; ++j) acc[i][j] = pb[c0 + j];

  #pragma unroll
  for (int ky = 0; ky < 3; ++ky){
    #pragma unroll
    for (int kx = 0; kx < 3; ++kx){
      f16x8 wv = *(const f16x8*)(pegq + ((ky * 3 + kx) << 8) + c0);
      #pragma unroll
      for (int i = 0; i < 4; ++i){
        int ww = (q << 2) + i + kx - 1;
        if ((u32)ww < 32u){
          f16x8 v = *(const f16x8*)(&tile[ky][ww][c0]);
          #pragma unroll
          for (int j = 0; j < 8; ++j) acc[i][j] += (float)v[j] * (float)wv[j];
        }
      }
    }
  }

  f32x4 iv0 = *(const f32x4*)(inv1 + c0), iv1 = *(const f32x4*)(inv1 + c0 + 4);
  f32x4 bt0 = *(const f32x4*)(bt1 + c0),  bt1v = *(const f32x4*)(bt1 + c0 + 4);
  #pragma unroll
  for (int i = 0; i < 4; ++i){
    f16x8 o;
    #pragma unroll
    for (int j = 0; j < 8; ++j){
      float ivj = (j < 4) ? iv0[j] : iv1[j - 4];
      float btj = (j < 4) ? bt0[j] : bt1v[j - 4];
      o[j] = (f16)fmaxf(acc[i][j] * ivj + btj, 0.0f);
    }
    int p = (h << 5) + (q << 2) + i;
    *(f16x8*)(h2T + (((size_t)(b << 10) + p) << 8) + c0) = o;
  }
}

// ---- conv2: 3x3 256->256. Block = 128 px x full 256 co, 8 waves; A staged
// once (pure copy); B double-buffered. bn2+relu -> h3T (WS_H1T region). ----
__global__ __launch_bounds__(512) void conv2_kernel(char* ws){
  __shared__ __align__(16) char lds[104448 + 32768];
  const f16* h2T = (const f16*)(ws + WS_H2T);
  const f16* w2q = (const f16*)(ws + WS_W2Q);
  const float* inv2 = (const float*)(ws + WS_BN2_INV);
  const float* bt2  = (const float*)(ws + WS_BN2_BETA);
  f16* h3T = (f16*)(ws + WS_H1T);

  int tid = threadIdx.x, bid = blockIdx.x;
  int b = bid >> 3, mt = bid & 7;
  int h0 = mt << 2;
  int m0 = mt << 7;
  int l = tid & 63, wid = tid >> 6, wm = wid >> 2, wn = wid & 3;
  int lr = l & 15, lg = l >> 4;
  char* A = lds;
  char* B0 = lds + 104448;
  char* B1 = lds + 104448 + 16384;

  for (int chunk = tid; chunk < 6528; chunk += 512){
    int r = chunk / 1088;
    int rem = chunk - r * 1088;
    int cc = rem >> 5, slot = rem & 31;
    int hh = h0 - 1 + r, wwp = cc - 1;
    u32x4 d = {0u, 0u, 0u, 0u};
    if ((u32)hh < 32u && (u32)wwp < 32u)
      d = *(const u32x4*)(h2T + (((size_t)(b << 10) + (hh << 5) + wwp) << 8) + (slot << 3));
    int sw = slot ^ ((cc & 7) << 2);
    *(u32x4*)(A + ((r * 34 + cc) << 9) + (sw << 4)) = d;
  }
  #pragma unroll
  for (int i = 0; i < 2; ++i){
    int chunk = tid + (i << 9);
    int co = chunk >> 2, slot = chunk & 3;
    u32x4 d = *(const u32x4*)(w2q + (co << 8) + (slot << 3));
    *(u32x4*)(B0 + (co << 6) + (SWZ(co, slot) << 4)) = d;
  }
  __syncthreads();

  f32x4 acc[4][4] = {};
  for (int tap = 0; tap < 9; ++tap){
    int dy = tap / 3 - 1, dx = tap % 3 - 1;
    int rowbase[4], key[4];
    #pragma unroll
    for (int mf = 0; mf < 4; ++mf){
      int p = (wm << 6) + (mf << 4) + lr;
      int rr = (p >> 5) + dy + 1;
      int cc = (p & 31) + dx + 1;
      rowbase[mf] = ((rr * 34 + cc) << 9) + (lg << 4);
      key[mf] = cc & 7;
    }
    #pragma unroll 2
    for (int ks = 0; ks < 8; ++ks){
      int t = (tap << 3) + ks;
      u32x4 st[2];
      int have = (t < 71);
      int t1 = t + 1, wtap = t1 >> 3, wks = t1 & 7;
      const f16* srcb = w2q + wtap * 65536 + (wks << 5);
      if (have){
        #pragma unroll
        for (int i = 0; i < 2; ++i){
          int chunk = tid + (i << 9);
          int co = chunk >> 2, slot = chunk & 3;
          st[i] = *(const u32x4*)(srcb + (co << 8) + (slot << 3));
        }
      }
      const char* bs = (t & 1) ? B1 : B0;
      f16x8 a[4], bb[4];
      #pragma unroll
      for (int mf = 0; mf < 4; ++mf)
        a[mf] = *(const f16x8*)(A + rowbase[mf] + ((ks ^ key[mf]) << 6));
      #pragma unroll
      for (int nf = 0; nf < 4; ++nf){
        int row = (wn << 6) + (nf << 4) + lr;
        bb[nf] = *(const f16x8*)(bs + (row << 6) + (SWZ(row, lg) << 4));
      }
      #pragma unroll
      for (int mf = 0; mf < 4; ++mf)
        #pragma unroll
        for (int nf = 0; nf < 4; ++nf)
          acc[mf][nf] = __builtin_amdgcn_mfma_f32_16x16x32_f16(a[mf], bb[nf], acc[mf][nf], 0, 0, 0);
      if (have){
        char* bd = (t1 & 1) ? B1 : B0;
        #pragma unroll
        for (int i = 0; i < 2; ++i){
          int chunk = tid + (i << 9);
          int co = chunk >> 2, slot = chunk & 3;
          *(u32x4*)(bd + (co << 6) + (SWZ(co, slot) << 4)) = st[i];
        }
      }
      __syncthreads();
    }
  }

  #pragma unroll
  for (int mf = 0; mf < 4; ++mf){
    int p0 = m0 + (wm << 6) + (mf << 4) + (lg << 2);
    size_t base = ((size_t)(b << 10) + p0) << 8;
    #pragma unroll
    for (int nf = 0; nf < 4; ++nf){
      int co = (wn << 6) + (nf << 4) + lr;
      float iv = inv2[co], bt = bt2[co];
      #pragma unroll
      for (int r = 0; r < 4; ++r)
        h3T[base + ((size_t)r << 8) + co] = (f16)fmaxf(acc[mf][nf][r] * iv + bt, 0.0f);
    }
  }
}

// ---- conv3: 1x1 256->1024. R10 plateau shape: 256 thr, grid 2048, linear
// bid, pure-copy staging, 2 barriers/step. bn3+residual+relu -> f32. ----
__global__ __launch_bounds__(256) void conv3_kernel(const float* __restrict__ x,
                                                    float* __restrict__ out, char* ws){
  __shared__ __align__(16) char lds[16384];
  const f16* w3q = (const f16*)(ws + WS_W3Q);
  const f16* h3T = (const f16*)(ws + WS_H1T);
  const float* inv3 = (const float*)(ws + WS_BN3_INV);
  const float* bt3  = (const float*)(ws + WS_BN3_BETA);

  int tid = threadIdx.x, bid = blockIdx.x;
  int b = bid >> 6, m0 = ((bid >> 3) & 7) << 7, n0 = (bid & 7) << 7;
  int l = tid & 63, wid = tid >> 6, wm = wid >> 1, wn = wid & 1;
  int lr = l & 15, lg = l >> 4;
  f32x4 acc[4][4] = {};

  for (int ks = 0; ks < 8; ++ks){
    int k0 = ks << 5;
    #pragma unroll
    for (int i = 0; i < 2; ++i){
      int s = tid + (i << 8);
      int row = s >> 2, slot = s & 3;
      u32x4 dA = *(const u32x4*)(w3q + ((size_t)(m0 + row) << 8) + k0 + (slot << 3));
      u32x4 dB = *(const u32x4*)(h3T + (((size_t)(b << 10) + n0 + row) << 8) + k0 + (slot << 3));
      *(u32x4*)(lds + (row << 6) + (SWZ(row, slot) << 4)) = dA;
      *(u32x4*)(lds + 8192 + (row << 6) + (SWZ(row, slot) << 4)) = dB;
    }
    __syncthreads();
    mfma_step(lds, wm, wn, lr, lg, acc);
    __syncthreads();
  }

  #pragma unroll
  for (int mf = 0; mf < 4; ++mf){
    int co0 = m0 + (wm << 6) + (mf << 4) + (lg << 2);
    f32x4 iv = *(const f32x4*)(inv3 + co0);
    f32x4 bt = *(const f32x4*)(bt3 + co0);
    #pragma unroll
    for (int nf = 0; nf < 4; ++nf){
      int p = n0 + (wn << 6) + (nf << 4) + lr;
      #pragma unroll
      for (int r = 0; r < 4; ++r){
        size_t idx = (((size_t)(b << 10) + co0 + r) << 10) + p;
        float z = acc[mf][nf][r] * iv[r] + bt[r] + x[idx];
        float rr = fmaxf(z, 0.0f);
        if (badf(z)) rr = 512.0f;
        out[idx] = rr;
      }
    }
  }
}

extern "C" void kernel_launch(void* const* d_in, const int* in_sizes, int n_in,
                              void* d_out, int out_size, void* d_ws, size_t ws_size,
                              hipStream_t stream){
  const float* x    = (const float*)d_in[0];
  const float* w1   = (const float*)d_in[1];
  const float* pegw = (const float*)d_in[2];
  const float* pegb = (const float*)d_in[3];
  const float* w2   = (const float*)d_in[4];
  const float* w3   = (const float*)d_in[5];
  const float* g1 = (const float*)d_in[6];
  const float* b1 = (const float*)d_in[7];
  const float* m1 = (const float*)d_in[8];
  const float* v1 = (const float*)d_in[9];
  const float* g2 = (const float*)d_in[10];
  const float* b2 = (const float*)d_in[11];
  const float* m2 = (const float*)d_in[12];
  const float* v2 = (const float*)d_in[13];
  const float* g3 = (const float*)d_in[14];
  const float* b3 = (const float*)d_in[15];
  const float* m3 = (const float*)d_in[16];
  const float* v3 = (const float*)d_in[17];
  char* ws = (char*)d_ws;

  prep_kernel<<<4368, 256, 0, stream>>>(w1, pegw, pegb, w2, w3,
                                        g1, b1, m1, v1, g2, b2, m2, v2,
                                        g3, b3, m3, v3, ws);
  conv1_kernel<<<256, 512, 0, stream>>>(x, ws);
  peg_kernel<<<1024, 256, 0, stream>>>(ws);
  conv2_kernel<<<256, 512, 0, stream>>>(ws);
  conv3_kernel<<<2048, 256, 0, stream>>>(x, (float*)d_out, ws);
}

// Round 15
// 169.697 us; speedup vs baseline: 1.1457x; 1.0456x over previous
//
#include <hip/hip_runtime.h>

typedef _Float16 f16;
typedef _Float16 f16x8 __attribute__((ext_vector_type(8)));
typedef float f32x4 __attribute__((ext_vector_type(4)));
typedef unsigned short u16;
typedef unsigned int u32;
typedef u32 u32x4 __attribute__((ext_vector_type(4)));

// ---- workspace layout (bytes) ----
#define WS_BN1_INV  256u       // 256 f32
#define WS_BN1_BETA 1280u
#define WS_BN2_INV  2304u
#define WS_BN2_BETA 3328u
#define WS_BN3_INV  4352u      // 1024 f32
#define WS_BN3_BETA 8448u
#define WS_PEG_B    12544u     // 256 f32
#define WS_PEGQ     13568u     // [9][256] f16
#define WS_W1Q      18432u     // [256 co][1024 ci] f16
#define WS_W3Q      542720u    // [1024 co][256 ci] f16
#define WS_W2Q      1067008u   // [9 tap][256 co][256 ci] f16
#define WS_H1T      2246656u   // [32768 p][256 c] f16
#define WS_H2T      19023872u  // [32768 p][256 c] f16

// r11: activation fake-quant subsumed by f16 rounding — removed (-66us).
// r13/r14: dbuf single-barrier conv1 (-17us). conv3 schedule plateau at ~75us
//   (5 variants) -> r15: FUSE conv3 into conv2 (h3 stays in LDS; x/out stream
//   overlaps the 2nd GEMM's MFMAs instead of running latency-bound alone).

__device__ __forceinline__ int badf(float f){
  union { float f; u32 u; } c; c.f = f;
  return (c.u & 0x7f800000u) == 0x7f800000u;
}
__device__ __forceinline__ float qpow2(float w){
  float a = fabsf(w) + 1e-20f;
  float p = rintf(log2f(a));
  p = fminf(fmaxf(p, -14.0f), 0.0f);
  float m = exp2f(p);
  return (w > 0.0f) ? m : ((w < 0.0f) ? -m : 0.0f);
}
__device__ __forceinline__ u32 pack2(float a, float b){
  union { f16 h[2]; u32 u; } p; p.h[0] = (f16)a; p.h[1] = (f16)b; return p.u;
}
#define SWZ(row, slot) ((((slot) ^ ((row) >> 1) ^ ((row) >> 3))) & 3)

// ---- prep: quantize all weights to f16 pow2, precompute BN affine ----
__global__ __launch_bounds__(256) void prep_kernel(
    const float* __restrict__ w1, const float* __restrict__ pegw, const float* __restrict__ pegb,
    const float* __restrict__ w2, const float* __restrict__ w3,
    const float* g1, const float* b1, const float* m1, const float* v1,
    const float* g2, const float* b2, const float* m2, const float* v2,
    const float* g3, const float* b3, const float* m3, const float* v3,
    char* ws){
  int i = blockIdx.x * 256 + threadIdx.x;
  if (i < 262144){ ((f16*)(ws + WS_W1Q))[i] = (f16)qpow2(w1[i]); return; }
  i -= 262144;
  if (i < 589824){ // repack OIHW -> [tap][co][ci]
    int tap = i >> 16, rem = i & 65535;
    int co = rem >> 8, ci = rem & 255;
    ((f16*)(ws + WS_W2Q))[i] = (f16)qpow2(w2[(((co << 8) + ci) * 9) + tap]);
    return;
  }
  i -= 589824;
  if (i < 262144){ ((f16*)(ws + WS_W3Q))[i] = (f16)qpow2(w3[i]); return; }
  i -= 262144;
  if (i < 2304){ // [c][tap] -> [tap][c]
    int tap = i >> 8, c = i & 255;
    ((f16*)(ws + WS_PEGQ))[i] = (f16)qpow2(pegw[c * 9 + tap]);
    return;
  }
  i -= 2304;
  if (i < 256){ ((float*)(ws + WS_PEG_B))[i] = pegb[i]; return; }
  i -= 256;
  if (i < 256){
    float inv = g1[i] / sqrtf(v1[i] + 1e-5f);
    ((float*)(ws + WS_BN1_INV))[i] = inv;
    ((float*)(ws + WS_BN1_BETA))[i] = b1[i] - m1[i] * inv;
    return;
  }
  i -= 256;
  if (i < 256){
    float inv = g2[i] / sqrtf(v2[i] + 1e-5f);
    ((float*)(ws + WS_BN2_INV))[i] = inv;
    ((float*)(ws + WS_BN2_BETA))[i] = b2[i] - m2[i] * inv;
    return;
  }
  i -= 256;
  if (i < 1024){
    float inv = g3[i] / sqrtf(v3[i] + 1e-5f);
    ((float*)(ws + WS_BN3_INV))[i] = inv;
    ((float*)(ws + WS_BN3_BETA))[i] = b3[i] - m3[i] * inv;
  }
}

// ---- conv1: 1x1 1024->256. Block = 128 px x FULL 256 co, 8 waves,
// double-buffered single-barrier (r14, measured win). ----
__global__ __launch_bounds__(512) void conv1_kernel(const float* __restrict__ x, char* ws){
  __shared__ __align__(16) char lds[49152];   // 2 x (A 8KB | B 16KB)
  const f16* w1q = (const f16*)(ws + WS_W1Q);
  f16* h1T = (f16*)(ws + WS_H1T);

  int tid = threadIdx.x, bid = blockIdx.x;
  int b = bid >> 3, m0 = (bid & 7) << 7;
  int l = tid & 63, wid = tid >> 6, wm = wid >> 2, wn = wid & 3;
  int lr = l & 15, lg = l >> 4;
  f32x4 acc[4][4] = {};

  int q = tid & 31;
  int c = tid >> 5;
  const float* xb = x + (((size_t)(b << 10)) << 10) + m0 + (q << 2);
  int aslot = c >> 2, aoff = (c & 3) << 2;

  f32x4 d0, d1; u32x4 wb0, wb1;
  {
    const float* src = xb + (((size_t)(c << 1)) << 10);
    d0 = *(const f32x4*)src;
    d1 = *(const f32x4*)(src + 1024);
    int s0 = tid, r0 = s0 >> 2, sl0 = s0 & 3;
    int s1 = tid + 512, r1 = s1 >> 2, sl1 = s1 & 3;
    wb0 = *(const u32x4*)(w1q + ((size_t)r0 << 10) + (sl0 << 3));
    wb1 = *(const u32x4*)(w1q + ((size_t)r1 << 10) + (sl1 << 3));
  }
  {
    char* A = lds;
    #pragma unroll
    for (int j = 0; j < 4; ++j){
      int row = (q << 2) + j;
      *(u32*)(A + (row << 6) + (SWZ(row, aslot) << 4) + aoff) = pack2(d0[j], d1[j]);
    }
    int s0 = tid, r0 = s0 >> 2, sl0 = s0 & 3;
    int s1 = tid + 512, r1 = s1 >> 2, sl1 = s1 & 3;
    *(u32x4*)(lds + 8192 + (r0 << 6) + (SWZ(r0, sl0) << 4)) = wb0;
    *(u32x4*)(lds + 8192 + (r1 << 6) + (SWZ(r1, sl1) << 4)) = wb1;
  }
  __syncthreads();

  for (int ks = 0; ks < 32; ++ks){
    const char* cur = lds + ((ks & 1) ? 24576 : 0);
    char* nxt = lds + ((ks & 1) ? 0 : 24576);
    if (ks < 31){
      int k0 = (ks + 1) << 5;
      const float* src = xb + (((size_t)(k0 + (c << 1))) << 10);
      d0 = *(const f32x4*)src;
      d1 = *(const f32x4*)(src + 1024);
      int s0 = tid, r0 = s0 >> 2, sl0 = s0 & 3;
      int s1 = tid + 512, r1 = s1 >> 2, sl1 = s1 & 3;
      wb0 = *(const u32x4*)(w1q + ((size_t)r0 << 10) + k0 + (sl0 << 3));
      wb1 = *(const u32x4*)(w1q + ((size_t)r1 << 10) + k0 + (sl1 << 3));
    }
    f16x8 a[4], bb[4];
    #pragma unroll
    for (int mf = 0; mf < 4; ++mf){
      int row = (wm << 6) + (mf << 4) + lr;
      a[mf] = *(const f16x8*)(cur + (row << 6) + (SWZ(row, lg) << 4));
    }
    #pragma unroll
    for (int nf = 0; nf < 4; ++nf){
      int row = (wn << 6) + (nf << 4) + lr;
      bb[nf] = *(const f16x8*)(cur + 8192 + (row << 6) + (SWZ(row, lg) << 4));
    }
    #pragma unroll
    for (int mf = 0; mf < 4; ++mf)
      #pragma unroll
      for (int nf = 0; nf < 4; ++nf)
        acc[mf][nf] = __builtin_amdgcn_mfma_f32_16x16x32_f16(a[mf], bb[nf], acc[mf][nf], 0, 0, 0);
    if (ks < 31){
      #pragma unroll
      for (int j = 0; j < 4; ++j){
        int row = (q << 2) + j;
        *(u32*)(nxt + (row << 6) + (SWZ(row, aslot) << 4) + aoff) = pack2(d0[j], d1[j]);
      }
      int s0 = tid, r0 = s0 >> 2, sl0 = s0 & 3;
      int s1 = tid + 512, r1 = s1 >> 2, sl1 = s1 & 3;
      *(u32x4*)(nxt + 8192 + (r0 << 6) + (SWZ(r0, sl0) << 4)) = wb0;
      *(u32x4*)(nxt + 8192 + (r1 << 6) + (SWZ(r1, sl1) << 4)) = wb1;
    }
    __syncthreads();
  }

  #pragma unroll
  for (int mf = 0; mf < 4; ++mf){
    int p0 = m0 + (wm << 6) + (mf << 4) + (lg << 2);
    size_t base = ((size_t)(b << 10) + p0) << 8;
    #pragma unroll
    for (int nf = 0; nf < 4; ++nf){
      int co = (wn << 6) + (nf << 4) + lr;
      #pragma unroll
      for (int r = 0; r < 4; ++r)
        h1T[base + ((size_t)r << 8) + co] = (f16)acc[mf][nf][r];
    }
  }
}

// ---- PEG: depthwise 3x3, block = one (batch,row); staging is a pure copy ----
__global__ __launch_bounds__(256) void peg_kernel(char* ws){
  __shared__ __align__(16) f16 tile[3][32][256];   // 48 KB
  const f16* h1T = (const f16*)(ws + WS_H1T);
  const f16* pegq = (const f16*)(ws + WS_PEGQ);
  const float* pb  = (const float*)(ws + WS_PEG_B);
  const float* inv1 = (const float*)(ws + WS_BN1_INV);
  const float* bt1  = (const float*)(ws + WS_BN1_BETA);
  f16* h2T = (f16*)(ws + WS_H2T);

  int tid = threadIdx.x;
  int b = blockIdx.x >> 5, h = blockIdx.x & 31;

  #pragma unroll
  for (int r = 0; r < 3; ++r){
    int hh = h + r - 1;
    #pragma unroll
    for (int i = 0; i < 4; ++i){
      int chunk = tid + (i << 8);
      int px = chunk >> 5, cg = chunk & 31;
      u32x4 d = {0u, 0u, 0u, 0u};
      if ((u32)hh < 32u)
        d = *(const u32x4*)(h1T + (((size_t)(b << 10) + (hh << 5) + px) << 8) + (cg << 3));
      *(u32x4*)(&tile[r][px][cg << 3]) = d;
    }
  }
  __syncthreads();

  int c0 = (tid & 31) << 3;
  int q  = tid >> 5;
  float acc[4][8];
  #pragma unroll
  for (int i = 0; i < 4; ++i)
    #pragma unroll
    for (int j = 0; j < 8; ++j) acc[i][j] = pb[c0 + j];

  #pragma unroll
  for (int ky = 0; ky < 3; ++ky){
    #pragma unroll
    for (int kx = 0; kx < 3; ++kx){
      f16x8 wv = *(const f16x8*)(pegq + ((ky * 3 + kx) << 8) + c0);
      #pragma unroll
      for (int i = 0; i < 4; ++i){
        int ww = (q << 2) + i + kx - 1;
        if ((u32)ww < 32u){
          f16x8 v = *(const f16x8*)(&tile[ky][ww][c0]);
          #pragma unroll
          for (int j = 0; j < 8; ++j) acc[i][j] += (float)v[j] * (float)wv[j];
        }
      }
    }
  }

  f32x4 iv0 = *(const f32x4*)(inv1 + c0), iv1 = *(const f32x4*)(inv1 + c0 + 4);
  f32x4 bt0 = *(const f32x4*)(bt1 + c0),  bt1v = *(const f32x4*)(bt1 + c0 + 4);
  #pragma unroll
  for (int i = 0; i < 4; ++i){
    f16x8 o;
    #pragma unroll
    for (int j = 0; j < 8; ++j){
      float ivj = (j < 4) ? iv0[j] : iv1[j - 4];
      float btj = (j < 4) ? bt0[j] : bt1v[j - 4];
      o[j] = (f16)fmaxf(acc[i][j] * ivj + btj, 0.0f);
    }
    int p = (h << 5) + (q << 2) + i;
    *(f16x8*)(h2T + (((size_t)(b << 10) + p) << 8) + c0) = o;
  }
}

// ---- conv23 (FUSED): conv2 3x3 256->256 (h3 kept in LDS) + conv3 1x1
// 256->1024 + bn3 + residual + relu -> out. Block = 128 px x everything.
// Phase 2's x/out stream (268 MB chip-wide) overlaps the 2nd GEMM's MFMAs. ----
__global__ __launch_bounds__(512) void conv23_kernel(const float* __restrict__ x,
                                                     float* __restrict__ out, char* ws){
  __shared__ __align__(16) char lds[137216];  // ph1: A 104448 + Bdbuf 32768; ph2: h3 64K + w3 64K
  const f16* h2T = (const f16*)(ws + WS_H2T);
  const f16* w2q = (const f16*)(ws + WS_W2Q);
  const f16* w3q = (const f16*)(ws + WS_W3Q);
  const float* inv2 = (const float*)(ws + WS_BN2_INV);
  const float* bt2  = (const float*)(ws + WS_BN2_BETA);
  const float* inv3 = (const float*)(ws + WS_BN3_INV);
  const float* bt3  = (const float*)(ws + WS_BN3_BETA);

  int tid = threadIdx.x, bid = blockIdx.x;
  int b = bid >> 3, mt = bid & 7;
  int h0 = mt << 2;
  int m0 = mt << 7;
  int l = tid & 63, wid = tid >> 6, wm = wid >> 2, wn = wid & 3;
  int lr = l & 15, lg = l >> 4;
  char* A = lds;
  char* B0 = lds + 104448;
  char* B1 = lds + 104448 + 16384;

  // ===== phase 1: conv2 (A staged once; B double-buffered) =====
  for (int chunk = tid; chunk < 6528; chunk += 512){
    int r = chunk / 1088;
    int rem = chunk - r * 1088;
    int cc = rem >> 5, slot = rem & 31;
    int hh = h0 - 1 + r, wwp = cc - 1;
    u32x4 d = {0u, 0u, 0u, 0u};
    if ((u32)hh < 32u && (u32)wwp < 32u)
      d = *(const u32x4*)(h2T + (((size_t)(b << 10) + (hh << 5) + wwp) << 8) + (slot << 3));
    int sw = slot ^ ((cc & 7) << 2);
    *(u32x4*)(A + ((r * 34 + cc) << 9) + (sw << 4)) = d;
  }
  #pragma unroll
  for (int i = 0; i < 2; ++i){
    int chunk = tid + (i << 9);
    int co = chunk >> 2, slot = chunk & 3;
    u32x4 d = *(const u32x4*)(w2q + (co << 8) + (slot << 3));
    *(u32x4*)(B0 + (co << 6) + (SWZ(co, slot) << 4)) = d;
  }
  __syncthreads();

  f32x4 acc[4][4] = {};
  for (int tap = 0; tap < 9; ++tap){
    int dy = tap / 3 - 1, dx = tap % 3 - 1;
    int rowbase[4], key[4];
    #pragma unroll
    for (int mf = 0; mf < 4; ++mf){
      int p = (wm << 6) + (mf << 4) + lr;
      int rr = (p >> 5) + dy + 1;
      int cc = (p & 31) + dx + 1;
      rowbase[mf] = ((rr * 34 + cc) << 9) + (lg << 4);
      key[mf] = cc & 7;
    }
    #pragma unroll 2
    for (int ks = 0; ks < 8; ++ks){
      int t = (tap << 3) + ks;
      u32x4 st[2];
      int have = (t < 71);
      int t1 = t + 1, wtap = t1 >> 3, wks = t1 & 7;
      const f16* srcb = w2q + wtap * 65536 + (wks << 5);
      if (have){
        #pragma unroll
        for (int i = 0; i < 2; ++i){
          int chunk = tid + (i << 9);
          int co = chunk >> 2, slot = chunk & 3;
          st[i] = *(const u32x4*)(srcb + (co << 8) + (slot << 3));
        }
      }
      const char* bs = (t & 1) ? B1 : B0;
      f16x8 a[4], bb[4];
      #pragma unroll
      for (int mf = 0; mf < 4; ++mf)
        a[mf] = *(const f16x8*)(A + rowbase[mf] + ((ks ^ key[mf]) << 6));
      #pragma unroll
      for (int nf = 0; nf < 4; ++nf){
        int row = (wn << 6) + (nf << 4) + lr;
        bb[nf] = *(const f16x8*)(bs + (row << 6) + (SWZ(row, lg) << 4));
      }
      #pragma unroll
      for (int mf = 0; mf < 4; ++mf)
        #pragma unroll
        for (int nf = 0; nf < 4; ++nf)
          acc[mf][nf] = __builtin_amdgcn_mfma_f32_16x16x32_f16(a[mf], bb[nf], acc[mf][nf], 0, 0, 0);
      if (have){
        char* bd = (t1 & 1) ? B1 : B0;
        #pragma unroll
        for (int i = 0; i < 2; ++i){
          int chunk = tid + (i << 9);
          int co = chunk >> 2, slot = chunk & 3;
          *(u32x4*)(bd + (co << 6) + (SWZ(co, slot) << 4)) = st[i];
        }
      }
      __syncthreads();
    }
  }

  // ===== h3 = bn2+relu(acc) -> LDS [128 px][256 c], 512B rows, swizzled =====
  // byte = px*512 + ((c>>3) ^ ((px&7)<<2))*16 + (c&7)*2
  #pragma unroll
  for (int mf = 0; mf < 4; ++mf){
    #pragma unroll
    for (int nf = 0; nf < 4; ++nf){
      int c = (wn << 6) + (nf << 4) + lr;
      float iv = inv2[c], bt = bt2[c];
      int slot = c >> 3, off = (c & 7) << 1;
      #pragma unroll
      for (int r = 0; r < 4; ++r){
        int px = (wm << 6) + (mf << 4) + (lg << 2) + r;
        float f = fmaxf(acc[mf][nf][r] * iv + bt, 0.0f);
        *(f16*)(lds + (px << 9) + ((slot ^ ((px & 7) << 2)) << 4) + off) = (f16)f;
      }
    }
  }
  __syncthreads();

  // ===== phase 2: conv3 over 8 co-tiles of 128; h3 in LDS, w3 tile staged =====
  // wave grid: wm2 (co half of 64) = wid>>2, wn2 (px quarter of 32) = wid&3
  for (int cot = 0; cot < 8; ++cot){
    // stage w3 tile [128 co][256 ci] -> lds+65536, same 512B-row swizzle
    #pragma unroll
    for (int i = 0; i < 8; ++i){
      int s = tid + (i << 9);
      int row = s >> 5, slot = s & 31;
      u32x4 d = *(const u32x4*)(w3q + (((size_t)(cot << 7) + row) << 8) + (slot << 3));
      *(u32x4*)(lds + 65536 + (row << 9) + ((slot ^ ((row & 7) << 2)) << 4)) = d;
    }
    __syncthreads();

    f32x4 acc2[4][2] = {};
    #pragma unroll
    for (int ks = 0; ks < 8; ++ks){
      f16x8 a[4], bb[2];
      #pragma unroll
      for (int mf = 0; mf < 4; ++mf){
        int row = (wm << 6) + (mf << 4) + lr;
        int slot = (ks << 2) | lg;
        a[mf] = *(const f16x8*)(lds + 65536 + (row << 9) + ((slot ^ ((row & 7) << 2)) << 4));
      }
      #pragma unroll
      for (int nf = 0; nf < 2; ++nf){
        int row = (wn << 5) + (nf << 4) + lr;
        int slot = (ks << 2) | lg;
        bb[nf] = *(const f16x8*)(lds + (row << 9) + ((slot ^ ((row & 7) << 2)) << 4));
      }
      #pragma unroll
      for (int mf = 0; mf < 4; ++mf)
        #pragma unroll
        for (int nf = 0; nf < 2; ++nf)
          acc2[mf][nf] = __builtin_amdgcn_mfma_f32_16x16x32_f16(a[mf], bb[nf], acc2[mf][nf], 0, 0, 0);
    }

    // epilogue: bn3 + residual + relu -> out (f32, coalesced over px)
    #pragma unroll
    for (int mf = 0; mf < 4; ++mf){
      int co0 = (cot << 7) + (wm << 6) + (mf << 4) + (lg << 2);
      f32x4 iv = *(const f32x4*)(inv3 + co0);
      f32x4 bt = *(const f32x4*)(bt3 + co0);
      float xr[8];
      #pragma unroll
      for (int nf = 0; nf < 2; ++nf){
        int px = (wn << 5) + (nf << 4) + lr;
        #pragma unroll
        for (int r = 0; r < 4; ++r)
          xr[(nf << 2) + r] = x[(((size_t)(b << 10) + co0 + r) << 10) + m0 + px];
      }
      #pragma unroll
      for (int nf = 0; nf < 2; ++nf){
        int px = (wn << 5) + (nf << 4) + lr;
        #pragma unroll
        for (int r = 0; r < 4; ++r){
          size_t idx = (((size_t)(b << 10) + co0 + r) << 10) + m0 + px;
          float z = acc2[mf][nf][r] * iv[r] + bt[r] + xr[(nf << 2) + r];
          float rr = fmaxf(z, 0.0f);
          if (badf(z)) rr = 512.0f;
          out[idx] = rr;
        }
      }
    }
    __syncthreads();
  }
}

extern "C" void kernel_launch(void* const* d_in, const int* in_sizes, int n_in,
                              void* d_out, int out_size, void* d_ws, size_t ws_size,
                              hipStream_t stream){
  const float* x    = (const float*)d_in[0];
  const float* w1   = (const float*)d_in[1];
  const float* pegw = (const float*)d_in[2];
  const float* pegb = (const float*)d_in[3];
  const float* w2   = (const float*)d_in[4];
  const float* w3   = (const float*)d_in[5];
  const float* g1 = (const float*)d_in[6];
  const float* b1 = (const float*)d_in[7];
  const float* m1 = (const float*)d_in[8];
  const float* v1 = (const float*)d_in[9];
  const float* g2 = (const float*)d_in[10];
  const float* b2 = (const float*)d_in[11];
  const float* m2 = (const float*)d_in[12];
  const float* v2 = (const float*)d_in[13];
  const float* g3 = (const float*)d_in[14];
  const float* b3 = (const float*)d_in[15];
  const float* m3 = (const float*)d_in[16];
  const float* v3 = (const float*)d_in[17];
  char* ws = (char*)d_ws;

  prep_kernel<<<4368, 256, 0, stream>>>(w1, pegw, pegb, w2, w3,
                                        g1, b1, m1, v1, g2, b2, m2, v2,
                                        g3, b3, m3, v3, ws);
  conv1_kernel<<<256, 512, 0, stream>>>(x, ws);
  peg_kernel<<<1024, 256, 0, stream>>>(ws);
  conv23_kernel<<<256, 512, 0, stream>>>(x, (float*)d_out, ws);
}